// Round 1
// baseline (171.157 us; speedup 1.0000x reference)
//
#include <hip/hip_runtime.h>
#include <hip/hip_bf16.h>

// S4 layer: y = irfft( rfft(pad(u)) * (rfft(pad(K)) + D) )[:L]
// B=16, H=128, L=4096, N=64. All fp32.
// k_conv2: DUAL-ROW radix-16 FFT4096. Each 256-thread block carries TWO
// rows (b,h) and (b+8,h) as va[16]/vb[16] through one shared barrier
// network. Two 4096-float2 XOR-swizzled buffers = exactly 64 KB static
// LDS (2 blocks/CU); ILP (2 dependent chains/thread) replaces TLP that
// R3/R6/R7 showed doesn't help (barrier-phased structure).
// This round (latency pass):
//  - abt row PREFETCHED into 16xfloat4 regs at kernel entry (fwd FFT
//    covers the global latency; at 2 waves/SIMD the old mid-kernel loads
//    were exposed). VGPR 116 -> ~190 is free: LDS caps occupancy.
//  - tw_apply/tw_apply2 twiddles built by binary decomposition (depth
//    15 -> <=5 dependent cmuls, same instruction count).
//  - k_khat launch_bounds relaxed (only 128 blocks -> 1 block/CU; the
//    old (256,4) VGPR cap bought nothing and risked spill).
// launch_bounds (256,1) on conv2: never force VGPR below natural
// (R4/R5: forced caps spill v[16] to scratch; WRITE_SIZE 32768 KB is
// the no-spill signal).
// ws: [0,4MiB) atR 128x4096 float2 ; [4MiB,12MiB) abt 128x4096 float4
//   (abt scrambled in radix-16 order: slot tid+256c <-> k=kb+256c).

#define PI_F 3.14159265358979323846f

__device__ __forceinline__ float2 cmulf(float2 a, float2 b) {
  return make_float2(a.x * b.x - a.y * b.y, a.x * b.y + a.y * b.x);
}
__device__ __forceinline__ void cmul_set(float2& v, float wr, float wi) {
  v = make_float2(v.x * wr - v.y * wi, v.x * wi + v.y * wr);
}
__device__ __forceinline__ int ad(int k) { return k + (k >> 4); }   // pad-17
__device__ __forceinline__ int sw16(int j) { return j ^ ((j >> 4) & 15); }

template <int SIGN>
__device__ __forceinline__ void bfly4(float2& a, float2& b, float2& c,
                                      float2& d) {
  float t0x = a.x + c.x, t0y = a.y + c.y;
  float t1x = a.x - c.x, t1y = a.y - c.y;
  float t2x = b.x + d.x, t2y = b.y + d.y;
  float t3x = b.x - d.x, t3y = b.y - d.y;
  a = make_float2(t0x + t2x, t0y + t2y);
  c = make_float2(t0x - t2x, t0y - t2y);
  if (SIGN < 0) {
    b = make_float2(t1x + t3y, t1y - t3x);
    d = make_float2(t1x - t3y, t1y + t3x);
  } else {
    b = make_float2(t1x - t3y, t1y + t3x);
    d = make_float2(t1x + t3y, t1y - t3x);
  }
}

// in-register 16-point DFT, natural in / natural out, constant twiddles.
template <int SIGN>
__device__ __forceinline__ void fft16(float2 v[16]) {
  const float sg = (float)SIGN;
  const float C1 = 0.92387953251128674f;
  const float S1 = 0.38268343236508978f;
  const float R2 = 0.70710678118654752f;
  bfly4<SIGN>(v[0], v[4], v[8], v[12]);
  bfly4<SIGN>(v[1], v[5], v[9], v[13]);
  bfly4<SIGN>(v[2], v[6], v[10], v[14]);
  bfly4<SIGN>(v[3], v[7], v[11], v[15]);
  cmul_set(v[5], C1, sg * S1);
  cmul_set(v[6], R2, sg * R2);
  cmul_set(v[7], S1, sg * C1);
  cmul_set(v[9], R2, sg * R2);
  v[10] = make_float2(-sg * v[10].y, sg * v[10].x);
  cmul_set(v[11], -R2, sg * R2);
  cmul_set(v[13], S1, sg * C1);
  cmul_set(v[14], -R2, sg * R2);
  cmul_set(v[15], -C1, -sg * S1);
  float2 w[16];
#pragma unroll
  for (int g = 0; g < 4; ++g) {
    float2 x0 = v[4 * g], x1 = v[4 * g + 1], x2 = v[4 * g + 2],
           x3 = v[4 * g + 3];
    bfly4<SIGN>(x0, x1, x2, x3);
    w[g] = x0; w[g + 4] = x1; w[g + 8] = x2; w[g + 12] = x3;
  }
#pragma unroll
  for (int i = 0; i < 16; ++i) v[i] = w[i];
}

// Twiddle application, binary-decomposed powers: depth <=5 instead of a
// 15-deep serial cmul chain (same op count; dependency chain was exposed
// at 2 waves/SIMD).
__device__ __forceinline__ void tw_apply(float2 v[16], float ang) {
  float sn, cn;
  __sincosf(ang, &sn, &cn);
  float2 w1 = make_float2(cn, sn);
  float2 w2 = cmulf(w1, w1);
  float2 w3 = cmulf(w2, w1);
  float2 w4 = cmulf(w2, w2);
  float2 w5 = cmulf(w4, w1);
  float2 w6 = cmulf(w4, w2);
  float2 w7 = cmulf(w4, w3);
  float2 w8 = cmulf(w4, w4);
  v[1] = cmulf(v[1], w1);
  v[2] = cmulf(v[2], w2);
  v[3] = cmulf(v[3], w3);
  v[4] = cmulf(v[4], w4);
  v[5] = cmulf(v[5], w5);
  v[6] = cmulf(v[6], w6);
  v[7] = cmulf(v[7], w7);
  v[8] = cmulf(v[8], w8);
  v[9] = cmulf(v[9], cmulf(w8, w1));
  v[10] = cmulf(v[10], cmulf(w8, w2));
  v[11] = cmulf(v[11], cmulf(w8, w3));
  v[12] = cmulf(v[12], cmulf(w8, w4));
  v[13] = cmulf(v[13], cmulf(w8, w5));
  v[14] = cmulf(v[14], cmulf(w8, w6));
  v[15] = cmulf(v[15], cmulf(w8, w7));
}

// shared twiddles for two rows, binary-decomposed powers
__device__ __forceinline__ void tw_apply2(float2 va[16], float2 vb[16],
                                          float ang) {
  float sn, cn;
  __sincosf(ang, &sn, &cn);
  float2 w1 = make_float2(cn, sn);
  float2 w2 = cmulf(w1, w1);
  float2 w3 = cmulf(w2, w1);
  float2 w4 = cmulf(w2, w2);
  float2 w5 = cmulf(w4, w1);
  float2 w6 = cmulf(w4, w2);
  float2 w7 = cmulf(w4, w3);
  float2 w8 = cmulf(w4, w4);
  va[1] = cmulf(va[1], w1);   vb[1] = cmulf(vb[1], w1);
  va[2] = cmulf(va[2], w2);   vb[2] = cmulf(vb[2], w2);
  va[3] = cmulf(va[3], w3);   vb[3] = cmulf(vb[3], w3);
  va[4] = cmulf(va[4], w4);   vb[4] = cmulf(vb[4], w4);
  va[5] = cmulf(va[5], w5);   vb[5] = cmulf(vb[5], w5);
  va[6] = cmulf(va[6], w6);   vb[6] = cmulf(vb[6], w6);
  va[7] = cmulf(va[7], w7);   vb[7] = cmulf(vb[7], w7);
  va[8] = cmulf(va[8], w8);   vb[8] = cmulf(vb[8], w8);
  float2 t;
  t = cmulf(w8, w1);  va[9] = cmulf(va[9], t);    vb[9] = cmulf(vb[9], t);
  t = cmulf(w8, w2);  va[10] = cmulf(va[10], t);  vb[10] = cmulf(vb[10], t);
  t = cmulf(w8, w3);  va[11] = cmulf(va[11], t);  vb[11] = cmulf(vb[11], t);
  t = cmulf(w8, w4);  va[12] = cmulf(va[12], t);  vb[12] = cmulf(vb[12], t);
  t = cmulf(w8, w5);  va[13] = cmulf(va[13], t);  vb[13] = cmulf(vb[13], t);
  t = cmulf(w8, w6);  va[14] = cmulf(va[14], t);  vb[14] = cmulf(vb[14], t);
  t = cmulf(w8, w7);  va[15] = cmulf(va[15], t);  vb[15] = cmulf(vb[15], t);
}

// ======== pad-17 single-row machinery (k_khat only; proven) ========
template <int SIGN>
__device__ void fft4096_regs(float2 v[16], float2* lds, int tid) {
  const int a = tid & 15, g2 = tid >> 4;
  fft16<SIGN>(v);
  tw_apply(v, (float)SIGN * (2.0f * PI_F / 4096.0f) * (float)tid);
  __syncthreads();
#pragma unroll
  for (int g = 0; g < 16; ++g) lds[tid * 17 + g] = v[g];
  __syncthreads();
#pragma unroll
  for (int b = 0; b < 16; ++b) v[b] = lds[a * 17 + b * 272 + g2];
  fft16<SIGN>(v);
  tw_apply(v, (float)SIGN * (2.0f * PI_F / 256.0f) * (float)a);
  __syncthreads();
#pragma unroll
  for (int b = 0; b < 16; ++b) lds[g2 * 17 + b * 273 + a] = v[b];
  __syncthreads();
#pragma unroll
  for (int a2 = 0; a2 < 16; ++a2) v[a2] = lds[g2 * 17 + a * 273 + a2];
  fft16<SIGN>(v);
  // no trailing barrier; callers must __syncthreads before reusing lds.
}

// ======== dual-row swizzled forward: natural -> scrambled ========
template <int SIGN>
__device__ void fft4096_x2(float2 va[16], float2 vb[16], float2* A, float2* B,
                           int tid) {
  const int a = tid & 15, g2 = tid >> 4;
  fft16<SIGN>(va);
  fft16<SIGN>(vb);
  tw_apply2(va, vb, (float)SIGN * (2.0f * PI_F / 4096.0f) * (float)tid);
  __syncthreads();
#pragma unroll
  for (int g = 0; g < 16; ++g) {
    int s = (tid << 4) | (g ^ a);
    A[s] = va[g];
    B[s] = vb[g];
  }
  __syncthreads();
#pragma unroll
  for (int b = 0; b < 16; ++b) {
    int s = ((a + 16 * b) << 4) | (g2 ^ a);
    va[b] = A[s];
    vb[b] = B[s];
  }
  fft16<SIGN>(va);
  fft16<SIGN>(vb);
  tw_apply2(va, vb, (float)SIGN * (2.0f * PI_F / 256.0f) * (float)a);
  __syncthreads();
#pragma unroll
  for (int b = 0; b < 16; ++b) {
    int s = (g2 << 8) | (b << 4) | (a ^ b);
    A[s] = va[b];
    B[s] = vb[b];
  }
  __syncthreads();
#pragma unroll
  for (int a2 = 0; a2 < 16; ++a2) {
    int s = (g2 << 8) | (a << 4) | (a2 ^ a);
    va[a2] = A[s];
    vb[a2] = B[s];
  }
  fft16<SIGN>(va);
  fft16<SIGN>(vb);
  // no trailing barrier.
}

// ======== dual-row swizzled inverse: scrambled -> natural ========
template <int SIGN>
__device__ void fft4096_x2_s2n(float2 va[16], float2 vb[16], float2* A,
                               float2* B, int tid) {
  const int a = tid & 15, g2 = tid >> 4;
  fft16<SIGN>(va);
  fft16<SIGN>(vb);
  __syncthreads();  // guard callers' prior lds reads
#pragma unroll
  for (int r = 0; r < 16; ++r) {
    int s = (g2 << 8) | (a << 4) | (r ^ a);
    A[s] = va[r];
    B[s] = vb[r];
  }
  __syncthreads();
#pragma unroll
  for (int b = 0; b < 16; ++b) {
    int s = (g2 << 8) | (b << 4) | (a ^ b);
    va[b] = A[s];
    vb[b] = B[s];
  }
  tw_apply2(va, vb, (float)SIGN * (2.0f * PI_F / 256.0f) * (float)a);
  fft16<SIGN>(va);
  fft16<SIGN>(vb);
  __syncthreads();
#pragma unroll
  for (int r = 0; r < 16; ++r) {
    int s = ((16 * r + a) << 4) | (g2 ^ a);
    A[s] = va[r];
    B[s] = vb[r];
  }
  __syncthreads();
#pragma unroll
  for (int g = 0; g < 16; ++g) {
    int s = (tid << 4) | (g ^ a);
    va[g] = A[s];
    vb[g] = B[s];
  }
  tw_apply2(va, vb, (float)SIGN * (2.0f * PI_F / 4096.0f) * (float)tid);
  fft16<SIGN>(va);
  fft16<SIGN>(vb);
}

// ---------------- Kernel 1a: Cauchy sums -> atRoots (unchanged) ---------
__global__ __launch_bounds__(256) void k_cauchy(
    const float* __restrict__ Lre, const float* __restrict__ Lim,
    const float* __restrict__ Pri, const float* __restrict__ Bri,
    const float* __restrict__ Cri, const float* __restrict__ lstep,
    float2* __restrict__ atR) {
  __shared__ float4 pA[64];
  __shared__ float4 pB[64];
  __shared__ float2 pL[64];
  const int h = blockIdx.x >> 4;
  const int sub = blockIdx.x & 15;
  const int tid = threadIdx.x;
  if (tid < 64) {
    int base = h * 64 + tid;
    float lr = fminf(Lre[base], -1e-4f);
    float li = Lim[base];
    float pr = Pri[2 * base], pi = Pri[2 * base + 1];
    float br = Bri[2 * base], bi = Bri[2 * base + 1];
    float cr = Cri[2 * base], ci = Cri[2 * base + 1];
    pA[tid] = make_float4(cr * br + ci * bi, cr * bi - ci * br,
                          cr * pr + ci * pi, cr * pi - ci * pr);
    pB[tid] = make_float4(pr * br + pi * bi, pr * bi - pi * br,
                          pr * pr + pi * pi, 0.f);
    pL[tid] = make_float2(lr, li);
  }
  __syncthreads();
  const float istep = expf(-lstep[h]);
  const int m = sub * 256 + tid;
  float sn, cn;
  __sincosf(-(2.0f * PI_F / 4096.0f) * (float)m, &sn, &cn);
  const float trm = 0.5f * (1.0f + cn);
  const float tim = 0.5f * sn;
  const float qrm = (1.0f - cn) * istep;
  const float qim = -sn * istep;
  float S0 = 0.f, S1 = 0.f, S2 = 0.f, S3 = 0.f, S4 = 0.f, S5 = 0.f, S6 = 0.f,
        S7 = 0.f;
#pragma unroll 8
  for (int n = 0; n < 64; ++n) {
    float4 a = pA[n];
    float4 b = pB[n];
    float2 L = pL[n];
    float dr = qrm - (trm * L.x - tim * L.y);
    float di = qim - (trm * L.y + tim * L.x);
    float inv = __builtin_amdgcn_rcpf(dr * dr + di * di);
    float sr = dr * inv, si = -di * inv;
    S0 += a.x * sr - a.y * si;  S1 += a.x * si + a.y * sr;
    S2 += a.z * sr - a.w * si;  S3 += a.z * si + a.w * sr;
    S4 += b.x * sr - b.y * si;  S5 += b.x * si + b.y * sr;
    S6 += b.z * sr;             S7 += b.z * si;
  }
  float tS11r = trm * S6 - tim * S7;
  float tS11i = trm * S7 + tim * S6;
  float denr = 1.0f + tS11r, deni = tS11i;
  float dinv = 1.0f / (denr * denr + deni * deni);
  float P1r = S2 * S4 - S3 * S5;
  float P1i = S2 * S5 + S3 * S4;
  float P2r = trm * P1r - tim * P1i;
  float P2i = trm * P1i + tim * P1r;
  float Qr = (P2r * denr + P2i * deni) * dinv;
  float Qi = (P2i * denr - P2r * deni) * dinv;
  atR[h * 4096 + m] = make_float2(S0 - Qr, S1 - Qi);
}

// ------- Kernel 1b: atRoots -> alpha/beta table (radix-16 scramble) -----
// Only 128 blocks (1 block/CU on half the chip) -> no occupancy to buy
// with a VGPR cap; relaxed bounds let the allocator avoid spills.
__global__ __launch_bounds__(256) void k_khat(
    const float2* __restrict__ atR, const float* __restrict__ Dp,
    float4* __restrict__ abt) {
  __shared__ float2 lds[4368];
  const int h = blockIdx.x;
  const int tid = threadIdx.x;
  float2 v[16];
#pragma unroll
  for (int c = 0; c < 16; ++c) v[c] = atR[h * 4096 + tid + 256 * c];
  fft4096_regs<1>(v, lds, tid);  // unnormalized inverse -> zK (scrambled)
  const int kb = (tid >> 4) + 16 * (tid & 15);
  float* ldsf = (float*)lds;
  const float s = 1.0f / 4096.0f;
  __syncthreads();
#pragma unroll
  for (int al = 0; al < 16; ++al) ldsf[ad(kb + 256 * al)] = v[al].x * s;
  __syncthreads();
#pragma unroll
  for (int c = 0; c < 8; ++c) {
    int n = tid + 256 * c;
    v[c] = make_float2(ldsf[ad(2 * n)], ldsf[ad(2 * n + 1)]);
  }
#pragma unroll
  for (int c = 8; c < 16; ++c) v[c] = make_float2(0.f, 0.f);
  fft4096_regs<-1>(v, lds, tid);  // forward; scrambled
  __syncthreads();
#pragma unroll
  for (int al = 0; al < 16; ++al) lds[ad(kb + 256 * al)] = v[al];
  __syncthreads();
  const float Dh = Dp[h];
#pragma unroll
  for (int c = 0; c < 16; ++c) {
    int k = kb + 256 * c;
    float2 Zk = lds[ad(k)];
    float2 Zm = lds[ad((4096 - k) & 4095)];
    float Er = 0.5f * (Zk.x + Zm.x), Ei = 0.5f * (Zk.y - Zm.y);
    float Or = 0.5f * (Zk.y + Zm.y), Oi = 0.5f * (Zm.x - Zk.x);
    float s_, c_;
    __sincosf(-(PI_F / 4096.0f) * (float)k, &s_, &c_);
    float Gr = c_ * Or - s_ * Oi, Gi = c_ * Oi + s_ * Or;  // G = W*O
    float ar = (Er + Dh + s_ * Gr) * s;
    float ai = (Ei + s_ * Gi) * s;
    float br = (-c_ * Gi) * s;
    float bi = (c_ * Gr) * s;
    abt[h * 4096 + tid + 256 * c] = make_float4(ar, ai, br, bi);  // scrambled
  }
}

// ---------------- Kernel 2: dual-row FFT convolution ----------------
// 1024 blocks: block i does rows i and i+1024 (same h, batches b and b+8).
__global__ __launch_bounds__(256, 1) void k_conv2(
    const float* __restrict__ u, const float4* __restrict__ abt,
    float* __restrict__ y) {
  __shared__ float2 lds[8192];  // 64 KB: two 32 KB row buffers
  float2* A = lds;
  float2* B = lds + 4096;
  const int i = blockIdx.x;  // 0..1023
  const int h = i & 127;
  const int tid = threadIdx.x;
  const float2* uA = (const float2*)(u + (size_t)i * 4096);
  const float2* uB = (const float2*)(u + (size_t)(i + 1024) * 4096);
  // Prefetch the whole abt row for this h into registers NOW; the forward
  // FFT (~2k cycles) hides the global latency that was exposed mid-kernel
  // at 2 waves/SIMD. One row serves both batch rows. LDS (not VGPR) caps
  // occupancy, so the +64 VGPR are free.
  const float4* __restrict__ abrow = abt + h * 4096;
  float4 ab[16];
#pragma unroll
  for (int al = 0; al < 16; ++al) ab[al] = abrow[tid + 256 * al];
  float2 va[16], vb[16];
#pragma unroll
  for (int c = 0; c < 8; ++c) {
    va[c] = uA[tid + 256 * c];
    vb[c] = uB[tid + 256 * c];
  }
#pragma unroll
  for (int c = 8; c < 16; ++c) {
    va[c] = make_float2(0.f, 0.f);
    vb[c] = make_float2(0.f, 0.f);
  }
  fft4096_x2<-1>(va, vb, A, B, tid);  // forward; v[al]=Z[kb+256al]
  const int kb = (tid >> 4) + 16 * (tid & 15);
  __syncthreads();  // lagging T2 reads done before overwrite
#pragma unroll
  for (int al = 0; al < 16; ++al) {
    int s = sw16(kb + 256 * al);
    A[s] = va[al];
    B[s] = vb[al];
  }
  __syncthreads();
#pragma unroll
  for (int al = 0; al < 16; ++al) {
    int k = kb + 256 * al;
    int sp = sw16((4096 - k) & 4095);
    float2 Zma = A[sp];
    float2 Zmb = B[sp];
    float2 Za = va[al];
    float2 Zb = vb[al];
    va[al] =
        make_float2(ab[al].x * Za.x - ab[al].y * Za.y + ab[al].z * Zma.x +
                        ab[al].w * Zma.y,
                    ab[al].x * Za.y + ab[al].y * Za.x + ab[al].w * Zma.x -
                        ab[al].z * Zma.y);
    vb[al] =
        make_float2(ab[al].x * Zb.x - ab[al].y * Zb.y + ab[al].z * Zmb.x +
                        ab[al].w * Zmb.y,
                    ab[al].x * Zb.y + ab[al].y * Zb.x + ab[al].w * Zmb.x -
                        ab[al].z * Zmb.y);
  }
  fft4096_x2_s2n<1>(va, vb, A, B, tid);  // inverse (scale folded in ab)
  float2* yA = (float2*)(y + (size_t)i * 4096);
  float2* yB = (float2*)(y + (size_t)(i + 1024) * 4096);
#pragma unroll
  for (int c = 0; c < 8; ++c) {
    yA[tid + 256 * c] = va[c];
    yB[tid + 256 * c] = vb[c];
  }
}

extern "C" void kernel_launch(void* const* d_in, const int* in_sizes, int n_in,
                              void* d_out, int out_size, void* d_ws,
                              size_t ws_size, hipStream_t stream) {
  (void)in_sizes; (void)n_in; (void)out_size; (void)ws_size;
  const float* u = (const float*)d_in[0];
  const float* Lre = (const float*)d_in[1];
  const float* Lim = (const float*)d_in[2];
  const float* Pri = (const float*)d_in[3];
  const float* Bri = (const float*)d_in[4];
  const float* Cri = (const float*)d_in[5];
  const float* lst = (const float*)d_in[6];
  const float* Dp = (const float*)d_in[7];
  float* y = (float*)d_out;
  float2* atR = (float2*)d_ws;                                     // 4 MiB
  float4* abt = (float4*)((char*)d_ws + (size_t)4 * 1024 * 1024);  // 8 MiB

  k_cauchy<<<2048, 256, 0, stream>>>(Lre, Lim, Pri, Bri, Cri, lst, atR);
  k_khat<<<128, 256, 0, stream>>>(atR, Dp, abt);
  k_conv2<<<1024, 256, 0, stream>>>(u, abt, y);
}

// Round 2
// 155.082 us; speedup vs baseline: 1.1037x; 1.1037x over previous
//
#include <hip/hip_runtime.h>
#include <hip/hip_bf16.h>

// S4 layer: y = irfft( rfft(pad(u)) * (rfft(pad(K)) + D) )[:L]
// B=16, H=128, L=4096, N=64. All fp32.
// k_conv2: DUAL-ROW radix-16 FFT4096. Each 256-thread block carries TWO
// rows (b,h) and (b+8,h) as va[16]/vb[16] through one shared barrier
// network. R1 lesson (REVERTED): abt reg-prefetch at entry + parallel
// twiddle temps raised VGPR 116->152 and the schedule degraded (43->56us,
// VALUBusy 48->38). Keep abt loads mid-kernel, serial twiddle chain.
// This round: A/B row buffers INTERLEAVED as one float4 LDS array (same
// 64 KB). A[s],B[s] were always accessed at the same s, so each b64
// pair becomes one ds_{read,write}_b128: DS instruction count halves
// (~320->~160/thread), bytes at 85 vs ~73 B/cyc, address math halves,
// zero extra register pressure (the packed quad IS the live va/vb pair).
// All five access patterns keep s&7 spanning 8 residues over consecutive
// 8 lanes (XOR swizzles) -> b128 at structural minimum, no new conflicts
// (watch SQ_LDS_BANK_CONFLICT ~0 as the check).
// launch_bounds (256,1): never force VGPR below natural (R4/R5: forced
// caps spill v[16] to scratch; WRITE_SIZE 32768 KB = no-spill signal).
// ws: [0,4MiB) atR 128x4096 float2 ; [4MiB,12MiB) abt 128x4096 float4
//   (abt scrambled in radix-16 order: slot tid+256c <-> k=kb+256c).

#define PI_F 3.14159265358979323846f

__device__ __forceinline__ float2 cmulf(float2 a, float2 b) {
  return make_float2(a.x * b.x - a.y * b.y, a.x * b.y + a.y * b.x);
}
__device__ __forceinline__ void cmul_set(float2& v, float wr, float wi) {
  v = make_float2(v.x * wr - v.y * wi, v.x * wi + v.y * wr);
}
__device__ __forceinline__ int ad(int k) { return k + (k >> 4); }   // pad-17
__device__ __forceinline__ int sw16(int j) { return j ^ ((j >> 4) & 15); }

template <int SIGN>
__device__ __forceinline__ void bfly4(float2& a, float2& b, float2& c,
                                      float2& d) {
  float t0x = a.x + c.x, t0y = a.y + c.y;
  float t1x = a.x - c.x, t1y = a.y - c.y;
  float t2x = b.x + d.x, t2y = b.y + d.y;
  float t3x = b.x - d.x, t3y = b.y - d.y;
  a = make_float2(t0x + t2x, t0y + t2y);
  c = make_float2(t0x - t2x, t0y - t2y);
  if (SIGN < 0) {
    b = make_float2(t1x + t3y, t1y - t3x);
    d = make_float2(t1x - t3y, t1y + t3x);
  } else {
    b = make_float2(t1x - t3y, t1y + t3x);
    d = make_float2(t1x + t3y, t1y - t3x);
  }
}

// in-register 16-point DFT, natural in / natural out, constant twiddles.
template <int SIGN>
__device__ __forceinline__ void fft16(float2 v[16]) {
  const float sg = (float)SIGN;
  const float C1 = 0.92387953251128674f;
  const float S1 = 0.38268343236508978f;
  const float R2 = 0.70710678118654752f;
  bfly4<SIGN>(v[0], v[4], v[8], v[12]);
  bfly4<SIGN>(v[1], v[5], v[9], v[13]);
  bfly4<SIGN>(v[2], v[6], v[10], v[14]);
  bfly4<SIGN>(v[3], v[7], v[11], v[15]);
  cmul_set(v[5], C1, sg * S1);
  cmul_set(v[6], R2, sg * R2);
  cmul_set(v[7], S1, sg * C1);
  cmul_set(v[9], R2, sg * R2);
  v[10] = make_float2(-sg * v[10].y, sg * v[10].x);
  cmul_set(v[11], -R2, sg * R2);
  cmul_set(v[13], S1, sg * C1);
  cmul_set(v[14], -R2, sg * R2);
  cmul_set(v[15], -C1, -sg * S1);
  float2 w[16];
#pragma unroll
  for (int g = 0; g < 4; ++g) {
    float2 x0 = v[4 * g], x1 = v[4 * g + 1], x2 = v[4 * g + 2],
           x3 = v[4 * g + 3];
    bfly4<SIGN>(x0, x1, x2, x3);
    w[g] = x0; w[g + 4] = x1; w[g + 8] = x2; w[g + 12] = x3;
  }
#pragma unroll
  for (int i = 0; i < 16; ++i) v[i] = w[i];
}

__device__ __forceinline__ void tw_apply(float2 v[16], float ang) {
  float sn, cn;
  __sincosf(ang, &sn, &cn);
  float2 w1 = make_float2(cn, sn), cw = w1;
#pragma unroll
  for (int g = 1; g < 16; ++g) {
    v[g] = cmulf(v[g], cw);
    if (g < 15) cw = cmulf(cw, w1);
  }
}

// shared-chain twiddle for two rows (R0-proven serial chain: low pressure)
__device__ __forceinline__ void tw_apply2(float2 va[16], float2 vb[16],
                                          float ang) {
  float sn, cn;
  __sincosf(ang, &sn, &cn);
  float2 w1 = make_float2(cn, sn), cw = w1;
#pragma unroll
  for (int g = 1; g < 16; ++g) {
    va[g] = cmulf(va[g], cw);
    vb[g] = cmulf(vb[g], cw);
    if (g < 15) cw = cmulf(cw, w1);
  }
}

// ======== pad-17 single-row machinery (k_khat only; proven) ========
template <int SIGN>
__device__ void fft4096_regs(float2 v[16], float2* lds, int tid) {
  const int a = tid & 15, g2 = tid >> 4;
  fft16<SIGN>(v);
  tw_apply(v, (float)SIGN * (2.0f * PI_F / 4096.0f) * (float)tid);
  __syncthreads();
#pragma unroll
  for (int g = 0; g < 16; ++g) lds[tid * 17 + g] = v[g];
  __syncthreads();
#pragma unroll
  for (int b = 0; b < 16; ++b) v[b] = lds[a * 17 + b * 272 + g2];
  fft16<SIGN>(v);
  tw_apply(v, (float)SIGN * (2.0f * PI_F / 256.0f) * (float)a);
  __syncthreads();
#pragma unroll
  for (int b = 0; b < 16; ++b) lds[g2 * 17 + b * 273 + a] = v[b];
  __syncthreads();
#pragma unroll
  for (int a2 = 0; a2 < 16; ++a2) v[a2] = lds[g2 * 17 + a * 273 + a2];
  fft16<SIGN>(v);
  // no trailing barrier; callers must __syncthreads before reusing lds.
}

// pack/unpack helpers for interleaved dual-row LDS (one b128 per pair)
__device__ __forceinline__ float4 pk(float2 a, float2 b) {
  return make_float4(a.x, a.y, b.x, b.y);
}

// ======== dual-row swizzled forward: natural -> scrambled ========
// AB[s] holds {rowA, rowB} interleaved: one ds_write_b128/ds_read_b128
// moves both rows (half the DS ops of split A/B buffers).
template <int SIGN>
__device__ void fft4096_x2(float2 va[16], float2 vb[16], float4* AB,
                           int tid) {
  const int a = tid & 15, g2 = tid >> 4;
  fft16<SIGN>(va);
  fft16<SIGN>(vb);
  tw_apply2(va, vb, (float)SIGN * (2.0f * PI_F / 4096.0f) * (float)tid);
  __syncthreads();
#pragma unroll
  for (int g = 0; g < 16; ++g) AB[(tid << 4) | (g ^ a)] = pk(va[g], vb[g]);
  __syncthreads();
#pragma unroll
  for (int b = 0; b < 16; ++b) {
    float4 t = AB[((a + 16 * b) << 4) | (g2 ^ a)];
    va[b] = make_float2(t.x, t.y);
    vb[b] = make_float2(t.z, t.w);
  }
  fft16<SIGN>(va);
  fft16<SIGN>(vb);
  tw_apply2(va, vb, (float)SIGN * (2.0f * PI_F / 256.0f) * (float)a);
  __syncthreads();
#pragma unroll
  for (int b = 0; b < 16; ++b)
    AB[(g2 << 8) | (b << 4) | (a ^ b)] = pk(va[b], vb[b]);
  __syncthreads();
#pragma unroll
  for (int a2 = 0; a2 < 16; ++a2) {
    float4 t = AB[(g2 << 8) | (a << 4) | (a2 ^ a)];
    va[a2] = make_float2(t.x, t.y);
    vb[a2] = make_float2(t.z, t.w);
  }
  fft16<SIGN>(va);
  fft16<SIGN>(vb);
  // no trailing barrier.
}

// ======== dual-row swizzled inverse: scrambled -> natural ========
template <int SIGN>
__device__ void fft4096_x2_s2n(float2 va[16], float2 vb[16], float4* AB,
                               int tid) {
  const int a = tid & 15, g2 = tid >> 4;
  fft16<SIGN>(va);
  fft16<SIGN>(vb);
  __syncthreads();  // guard callers' prior lds reads
#pragma unroll
  for (int r = 0; r < 16; ++r)
    AB[(g2 << 8) | (a << 4) | (r ^ a)] = pk(va[r], vb[r]);
  __syncthreads();
#pragma unroll
  for (int b = 0; b < 16; ++b) {
    float4 t = AB[(g2 << 8) | (b << 4) | (a ^ b)];
    va[b] = make_float2(t.x, t.y);
    vb[b] = make_float2(t.z, t.w);
  }
  tw_apply2(va, vb, (float)SIGN * (2.0f * PI_F / 256.0f) * (float)a);
  fft16<SIGN>(va);
  fft16<SIGN>(vb);
  __syncthreads();
#pragma unroll
  for (int r = 0; r < 16; ++r)
    AB[((16 * r + a) << 4) | (g2 ^ a)] = pk(va[r], vb[r]);
  __syncthreads();
#pragma unroll
  for (int g = 0; g < 16; ++g) {
    float4 t = AB[(tid << 4) | (g ^ a)];
    va[g] = make_float2(t.x, t.y);
    vb[g] = make_float2(t.z, t.w);
  }
  tw_apply2(va, vb, (float)SIGN * (2.0f * PI_F / 4096.0f) * (float)tid);
  fft16<SIGN>(va);
  fft16<SIGN>(vb);
}

// ---------------- Kernel 1a: Cauchy sums -> atRoots (unchanged) ---------
__global__ __launch_bounds__(256) void k_cauchy(
    const float* __restrict__ Lre, const float* __restrict__ Lim,
    const float* __restrict__ Pri, const float* __restrict__ Bri,
    const float* __restrict__ Cri, const float* __restrict__ lstep,
    float2* __restrict__ atR) {
  __shared__ float4 pA[64];
  __shared__ float4 pB[64];
  __shared__ float2 pL[64];
  const int h = blockIdx.x >> 4;
  const int sub = blockIdx.x & 15;
  const int tid = threadIdx.x;
  if (tid < 64) {
    int base = h * 64 + tid;
    float lr = fminf(Lre[base], -1e-4f);
    float li = Lim[base];
    float pr = Pri[2 * base], pi = Pri[2 * base + 1];
    float br = Bri[2 * base], bi = Bri[2 * base + 1];
    float cr = Cri[2 * base], ci = Cri[2 * base + 1];
    pA[tid] = make_float4(cr * br + ci * bi, cr * bi - ci * br,
                          cr * pr + ci * pi, cr * pi - ci * pr);
    pB[tid] = make_float4(pr * br + pi * bi, pr * bi - pi * br,
                          pr * pr + pi * pi, 0.f);
    pL[tid] = make_float2(lr, li);
  }
  __syncthreads();
  const float istep = expf(-lstep[h]);
  const int m = sub * 256 + tid;
  float sn, cn;
  __sincosf(-(2.0f * PI_F / 4096.0f) * (float)m, &sn, &cn);
  const float trm = 0.5f * (1.0f + cn);
  const float tim = 0.5f * sn;
  const float qrm = (1.0f - cn) * istep;
  const float qim = -sn * istep;
  float S0 = 0.f, S1 = 0.f, S2 = 0.f, S3 = 0.f, S4 = 0.f, S5 = 0.f, S6 = 0.f,
        S7 = 0.f;
#pragma unroll 8
  for (int n = 0; n < 64; ++n) {
    float4 a = pA[n];
    float4 b = pB[n];
    float2 L = pL[n];
    float dr = qrm - (trm * L.x - tim * L.y);
    float di = qim - (trm * L.y + tim * L.x);
    float inv = __builtin_amdgcn_rcpf(dr * dr + di * di);
    float sr = dr * inv, si = -di * inv;
    S0 += a.x * sr - a.y * si;  S1 += a.x * si + a.y * sr;
    S2 += a.z * sr - a.w * si;  S3 += a.z * si + a.w * sr;
    S4 += b.x * sr - b.y * si;  S5 += b.x * si + b.y * sr;
    S6 += b.z * sr;             S7 += b.z * si;
  }
  float tS11r = trm * S6 - tim * S7;
  float tS11i = trm * S7 + tim * S6;
  float denr = 1.0f + tS11r, deni = tS11i;
  float dinv = 1.0f / (denr * denr + deni * deni);
  float P1r = S2 * S4 - S3 * S5;
  float P1i = S2 * S5 + S3 * S4;
  float P2r = trm * P1r - tim * P1i;
  float P2i = trm * P1i + tim * P1r;
  float Qr = (P2r * denr + P2i * deni) * dinv;
  float Qi = (P2i * denr - P2r * deni) * dinv;
  atR[h * 4096 + m] = make_float2(S0 - Qr, S1 - Qi);
}

// ------- Kernel 1b: atRoots -> alpha/beta table (radix-16 scramble) -----
__global__ __launch_bounds__(256, 4) void k_khat(
    const float2* __restrict__ atR, const float* __restrict__ Dp,
    float4* __restrict__ abt) {
  __shared__ float2 lds[4368];
  const int h = blockIdx.x;
  const int tid = threadIdx.x;
  float2 v[16];
#pragma unroll
  for (int c = 0; c < 16; ++c) v[c] = atR[h * 4096 + tid + 256 * c];
  fft4096_regs<1>(v, lds, tid);  // unnormalized inverse -> zK (scrambled)
  const int kb = (tid >> 4) + 16 * (tid & 15);
  float* ldsf = (float*)lds;
  const float s = 1.0f / 4096.0f;
  __syncthreads();
#pragma unroll
  for (int al = 0; al < 16; ++al) ldsf[ad(kb + 256 * al)] = v[al].x * s;
  __syncthreads();
#pragma unroll
  for (int c = 0; c < 8; ++c) {
    int n = tid + 256 * c;
    v[c] = make_float2(ldsf[ad(2 * n)], ldsf[ad(2 * n + 1)]);
  }
#pragma unroll
  for (int c = 8; c < 16; ++c) v[c] = make_float2(0.f, 0.f);
  fft4096_regs<-1>(v, lds, tid);  // forward; scrambled
  __syncthreads();
#pragma unroll
  for (int al = 0; al < 16; ++al) lds[ad(kb + 256 * al)] = v[al];
  __syncthreads();
  const float Dh = Dp[h];
#pragma unroll
  for (int c = 0; c < 16; ++c) {
    int k = kb + 256 * c;
    float2 Zk = lds[ad(k)];
    float2 Zm = lds[ad((4096 - k) & 4095)];
    float Er = 0.5f * (Zk.x + Zm.x), Ei = 0.5f * (Zk.y - Zm.y);
    float Or = 0.5f * (Zk.y + Zm.y), Oi = 0.5f * (Zm.x - Zk.x);
    float s_, c_;
    __sincosf(-(PI_F / 4096.0f) * (float)k, &s_, &c_);
    float Gr = c_ * Or - s_ * Oi, Gi = c_ * Oi + s_ * Or;  // G = W*O
    float ar = (Er + Dh + s_ * Gr) * s;
    float ai = (Ei + s_ * Gi) * s;
    float br = (-c_ * Gi) * s;
    float bi = (c_ * Gr) * s;
    abt[h * 4096 + tid + 256 * c] = make_float4(ar, ai, br, bi);  // scrambled
  }
}

// ---------------- Kernel 2: dual-row FFT convolution ----------------
// 1024 blocks: block i does rows i and i+1024 (same h, batches b and b+8).
__global__ __launch_bounds__(256, 1) void k_conv2(
    const float* __restrict__ u, const float4* __restrict__ abt,
    float* __restrict__ y) {
  __shared__ float4 AB[4096];  // 64 KB: interleaved {rowA,rowB} per bin
  const int i = blockIdx.x;  // 0..1023
  const int h = i & 127;
  const int tid = threadIdx.x;
  const float2* uA = (const float2*)(u + (size_t)i * 4096);
  const float2* uB = (const float2*)(u + (size_t)(i + 1024) * 4096);
  float2 va[16], vb[16];
#pragma unroll
  for (int c = 0; c < 8; ++c) {
    va[c] = uA[tid + 256 * c];
    vb[c] = uB[tid + 256 * c];
  }
#pragma unroll
  for (int c = 8; c < 16; ++c) {
    va[c] = make_float2(0.f, 0.f);
    vb[c] = make_float2(0.f, 0.f);
  }
  fft4096_x2<-1>(va, vb, AB, tid);  // forward; v[al]=Z[kb+256al]
  const int kb = (tid >> 4) + 16 * (tid & 15);
  __syncthreads();  // lagging T2 reads done before overwrite
#pragma unroll
  for (int al = 0; al < 16; ++al)
    AB[sw16(kb + 256 * al)] = pk(va[al], vb[al]);
  __syncthreads();
  const float4* __restrict__ abrow = abt + h * 4096;
#pragma unroll
  for (int al = 0; al < 16; ++al) {
    int k = kb + 256 * al;
    float4 zm = AB[sw16((4096 - k) & 4095)];  // {Zma, Zmb} one b128
    float4 ab = abrow[tid + 256 * al];        // one load serves both rows
    float2 Zma = make_float2(zm.x, zm.y);
    float2 Zmb = make_float2(zm.z, zm.w);
    float2 Za = va[al];
    float2 Zb = vb[al];
    va[al] =
        make_float2(ab.x * Za.x - ab.y * Za.y + ab.z * Zma.x + ab.w * Zma.y,
                    ab.x * Za.y + ab.y * Za.x + ab.w * Zma.x - ab.z * Zma.y);
    vb[al] =
        make_float2(ab.x * Zb.x - ab.y * Zb.y + ab.z * Zmb.x + ab.w * Zmb.y,
                    ab.x * Zb.y + ab.y * Zb.x + ab.w * Zmb.x - ab.z * Zmb.y);
  }
  fft4096_x2_s2n<1>(va, vb, AB, tid);  // inverse (scale folded in ab)
  float2* yA = (float2*)(y + (size_t)i * 4096);
  float2* yB = (float2*)(y + (size_t)(i + 1024) * 4096);
#pragma unroll
  for (int c = 0; c < 8; ++c) {
    yA[tid + 256 * c] = va[c];
    yB[tid + 256 * c] = vb[c];
  }
}

extern "C" void kernel_launch(void* const* d_in, const int* in_sizes, int n_in,
                              void* d_out, int out_size, void* d_ws,
                              size_t ws_size, hipStream_t stream) {
  (void)in_sizes; (void)n_in; (void)out_size; (void)ws_size;
  const float* u = (const float*)d_in[0];
  const float* Lre = (const float*)d_in[1];
  const float* Lim = (const float*)d_in[2];
  const float* Pri = (const float*)d_in[3];
  const float* Bri = (const float*)d_in[4];
  const float* Cri = (const float*)d_in[5];
  const float* lst = (const float*)d_in[6];
  const float* Dp = (const float*)d_in[7];
  float* y = (float*)d_out;
  float2* atR = (float2*)d_ws;                                     // 4 MiB
  float4* abt = (float4*)((char*)d_ws + (size_t)4 * 1024 * 1024);  // 8 MiB

  k_cauchy<<<2048, 256, 0, stream>>>(Lre, Lim, Pri, Bri, Cri, lst, atR);
  k_khat<<<128, 256, 0, stream>>>(atR, Dp, abt);
  k_conv2<<<1024, 256, 0, stream>>>(u, abt, y);
}

// Round 3
// 146.388 us; speedup vs baseline: 1.1692x; 1.0594x over previous
//
#include <hip/hip_runtime.h>
#include <hip/hip_bf16.h>

// S4 layer: y = irfft( rfft(pad(u)) * (rfft(pad(K)) + D) )[:L]
// B=16, H=128, L=4096, N=64. All fp32.
// k_conv2: DUAL-ROW radix-16 FFT4096, interleaved float4 LDS (R2: b128
// pair moves both rows; DS ops halved, 41.6us). R1 lesson: no reg
// prefetch of abt, serial twiddle chain (pressure kills schedule).
// This round (VALU pass): ALL complex arithmetic rewritten as clang
// ext_vector float2 (v2) ops -> backend emits v_pk_{fma,add,mul}_f32
// with op_sel/neg folding. bfly4 16 scalar -> ~9 packed; cmul 4 -> 2.
// Shared by conv2+khat fft16/twiddle; cauchy inner loop packed too.
// Pure instruction-count change: LDS layout, barriers, occupancy
// untouched. Bounded downside: if v_pk is half-rate-per-instr it is
// FLOP-neutral, not worse.
// launch_bounds (256,1) conv2: never force VGPR below natural (forced
// caps spill v[16]; WRITE_SIZE 32768 KB = no-spill signal).
// ws: [0,4MiB) atR 128x4096 float2 ; [4MiB,12MiB) abt 128x4096 float4
//   (abt scrambled in radix-16 order: slot tid+256c <-> k=kb+256c).

#define PI_F 3.14159265358979323846f

typedef float v2 __attribute__((ext_vector_type(2)));

__device__ __forceinline__ v2 tov2(float2 a) { return (v2){a.x, a.y}; }
__device__ __forceinline__ float2 tof2(v2 a) { return make_float2(a.x, a.y); }

// packed complex mul: 2x v_pk (mul + fma), swizzles fold to op_sel/neg
__device__ __forceinline__ v2 cmul(v2 a, v2 b) {
  v2 t = __builtin_shufflevector(a, a, 0, 0) * b;          // (ax bx, ax by)
  v2 bs = __builtin_shufflevector(b, b, 1, 0);             // (by, bx)
  v2 m = (v2){-bs.x, bs.y};                                // (-by, bx)
  return __builtin_shufflevector(a, a, 1, 1) * m + t;
}
// packed complex mul by constant (wr, wi)
__device__ __forceinline__ v2 cmulc(v2 a, float wr, float wi) {
  v2 t = __builtin_shufflevector(a, a, 0, 0) * (v2){wr, wi};
  return __builtin_shufflevector(a, a, 1, 1) * (v2){-wi, wr} + t;
}
// a * conj(b), packed
__device__ __forceinline__ v2 cmulcj(v2 a, v2 b) {
  v2 bc = (v2){b.x, -b.y};
  return cmul(a, bc);
}

__device__ __forceinline__ int ad(int k) { return k + (k >> 4); }   // pad-17
__device__ __forceinline__ int sw16(int j) { return j ^ ((j >> 4) & 15); }

template <int SIGN>
__device__ __forceinline__ void bfly4(v2& a, v2& b, v2& c, v2& d) {
  v2 t0 = a + c, t1 = a - c, t2 = b + d, t3 = b - d;
  a = t0 + t2;
  c = t0 - t2;
  v2 t3i = (v2){t3.y, -t3.x};  // -i * t3 (times sign handling below)
  if (SIGN < 0) {
    b = t1 + t3i;
    d = t1 - t3i;
  } else {
    b = t1 - t3i;
    d = t1 + t3i;
  }
}

// in-register 16-point DFT, natural in / natural out, constant twiddles.
template <int SIGN>
__device__ __forceinline__ void fft16(v2 v[16]) {
  const float sg = (float)SIGN;
  const float C1 = 0.92387953251128674f;
  const float S1 = 0.38268343236508978f;
  const float R2 = 0.70710678118654752f;
  bfly4<SIGN>(v[0], v[4], v[8], v[12]);
  bfly4<SIGN>(v[1], v[5], v[9], v[13]);
  bfly4<SIGN>(v[2], v[6], v[10], v[14]);
  bfly4<SIGN>(v[3], v[7], v[11], v[15]);
  v[5] = cmulc(v[5], C1, sg * S1);
  v[6] = cmulc(v[6], R2, sg * R2);
  v[7] = cmulc(v[7], S1, sg * C1);
  v[9] = cmulc(v[9], R2, sg * R2);
  v[10] = (SIGN < 0) ? (v2){v[10].y, -v[10].x} : (v2){-v[10].y, v[10].x};
  v[11] = cmulc(v[11], -R2, sg * R2);
  v[13] = cmulc(v[13], S1, sg * C1);
  v[14] = cmulc(v[14], -R2, sg * R2);
  v[15] = cmulc(v[15], -C1, -sg * S1);
  v2 w[16];
#pragma unroll
  for (int g = 0; g < 4; ++g) {
    v2 x0 = v[4 * g], x1 = v[4 * g + 1], x2 = v[4 * g + 2], x3 = v[4 * g + 3];
    bfly4<SIGN>(x0, x1, x2, x3);
    w[g] = x0; w[g + 4] = x1; w[g + 8] = x2; w[g + 12] = x3;
  }
#pragma unroll
  for (int i = 0; i < 16; ++i) v[i] = w[i];
}

__device__ __forceinline__ void tw_apply(v2 v[16], float ang) {
  float sn, cn;
  __sincosf(ang, &sn, &cn);
  v2 w1 = (v2){cn, sn}, cw = w1;
#pragma unroll
  for (int g = 1; g < 16; ++g) {
    v[g] = cmul(v[g], cw);
    if (g < 15) cw = cmul(cw, w1);
  }
}

// shared-chain twiddle for two rows (R0-proven serial chain: low pressure)
__device__ __forceinline__ void tw_apply2(v2 va[16], v2 vb[16], float ang) {
  float sn, cn;
  __sincosf(ang, &sn, &cn);
  v2 w1 = (v2){cn, sn}, cw = w1;
#pragma unroll
  for (int g = 1; g < 16; ++g) {
    va[g] = cmul(va[g], cw);
    vb[g] = cmul(vb[g], cw);
    if (g < 15) cw = cmul(cw, w1);
  }
}

// ======== pad-17 single-row machinery (k_khat only; proven) ========
template <int SIGN>
__device__ void fft4096_regs(v2 v[16], float2* lds, int tid) {
  const int a = tid & 15, g2 = tid >> 4;
  fft16<SIGN>(v);
  tw_apply(v, (float)SIGN * (2.0f * PI_F / 4096.0f) * (float)tid);
  __syncthreads();
#pragma unroll
  for (int g = 0; g < 16; ++g) lds[tid * 17 + g] = tof2(v[g]);
  __syncthreads();
#pragma unroll
  for (int b = 0; b < 16; ++b) v[b] = tov2(lds[a * 17 + b * 272 + g2]);
  fft16<SIGN>(v);
  tw_apply(v, (float)SIGN * (2.0f * PI_F / 256.0f) * (float)a);
  __syncthreads();
#pragma unroll
  for (int b = 0; b < 16; ++b) lds[g2 * 17 + b * 273 + a] = tof2(v[b]);
  __syncthreads();
#pragma unroll
  for (int a2 = 0; a2 < 16; ++a2) v[a2] = tov2(lds[g2 * 17 + a * 273 + a2]);
  fft16<SIGN>(v);
  // no trailing barrier; callers must __syncthreads before reusing lds.
}

// pack/unpack helpers for interleaved dual-row LDS (one b128 per pair)
__device__ __forceinline__ float4 pk(v2 a, v2 b) {
  return make_float4(a.x, a.y, b.x, b.y);
}

// ======== dual-row swizzled forward: natural -> scrambled ========
// AB[s] holds {rowA, rowB} interleaved: one ds_write_b128/ds_read_b128
// moves both rows (half the DS ops of split A/B buffers).
template <int SIGN>
__device__ void fft4096_x2(v2 va[16], v2 vb[16], float4* AB, int tid) {
  const int a = tid & 15, g2 = tid >> 4;
  fft16<SIGN>(va);
  fft16<SIGN>(vb);
  tw_apply2(va, vb, (float)SIGN * (2.0f * PI_F / 4096.0f) * (float)tid);
  __syncthreads();
#pragma unroll
  for (int g = 0; g < 16; ++g) AB[(tid << 4) | (g ^ a)] = pk(va[g], vb[g]);
  __syncthreads();
#pragma unroll
  for (int b = 0; b < 16; ++b) {
    float4 t = AB[((a + 16 * b) << 4) | (g2 ^ a)];
    va[b] = (v2){t.x, t.y};
    vb[b] = (v2){t.z, t.w};
  }
  fft16<SIGN>(va);
  fft16<SIGN>(vb);
  tw_apply2(va, vb, (float)SIGN * (2.0f * PI_F / 256.0f) * (float)a);
  __syncthreads();
#pragma unroll
  for (int b = 0; b < 16; ++b)
    AB[(g2 << 8) | (b << 4) | (a ^ b)] = pk(va[b], vb[b]);
  __syncthreads();
#pragma unroll
  for (int a2 = 0; a2 < 16; ++a2) {
    float4 t = AB[(g2 << 8) | (a << 4) | (a2 ^ a)];
    va[a2] = (v2){t.x, t.y};
    vb[a2] = (v2){t.z, t.w};
  }
  fft16<SIGN>(va);
  fft16<SIGN>(vb);
  // no trailing barrier.
}

// ======== dual-row swizzled inverse: scrambled -> natural ========
template <int SIGN>
__device__ void fft4096_x2_s2n(v2 va[16], v2 vb[16], float4* AB, int tid) {
  const int a = tid & 15, g2 = tid >> 4;
  fft16<SIGN>(va);
  fft16<SIGN>(vb);
  __syncthreads();  // guard callers' prior lds reads
#pragma unroll
  for (int r = 0; r < 16; ++r)
    AB[(g2 << 8) | (a << 4) | (r ^ a)] = pk(va[r], vb[r]);
  __syncthreads();
#pragma unroll
  for (int b = 0; b < 16; ++b) {
    float4 t = AB[(g2 << 8) | (b << 4) | (a ^ b)];
    va[b] = (v2){t.x, t.y};
    vb[b] = (v2){t.z, t.w};
  }
  tw_apply2(va, vb, (float)SIGN * (2.0f * PI_F / 256.0f) * (float)a);
  fft16<SIGN>(va);
  fft16<SIGN>(vb);
  __syncthreads();
#pragma unroll
  for (int r = 0; r < 16; ++r)
    AB[((16 * r + a) << 4) | (g2 ^ a)] = pk(va[r], vb[r]);
  __syncthreads();
#pragma unroll
  for (int g = 0; g < 16; ++g) {
    float4 t = AB[(tid << 4) | (g ^ a)];
    va[g] = (v2){t.x, t.y};
    vb[g] = (v2){t.z, t.w};
  }
  tw_apply2(va, vb, (float)SIGN * (2.0f * PI_F / 4096.0f) * (float)tid);
  fft16<SIGN>(va);
  fft16<SIGN>(vb);
}

// ---------------- Kernel 1a: Cauchy sums -> atRoots (packed) ---------
__global__ __launch_bounds__(256) void k_cauchy(
    const float* __restrict__ Lre, const float* __restrict__ Lim,
    const float* __restrict__ Pri, const float* __restrict__ Bri,
    const float* __restrict__ Cri, const float* __restrict__ lstep,
    float2* __restrict__ atR) {
  __shared__ float4 pA[64];
  __shared__ float4 pB[64];
  __shared__ float2 pL[64];
  const int h = blockIdx.x >> 4;
  const int sub = blockIdx.x & 15;
  const int tid = threadIdx.x;
  if (tid < 64) {
    int base = h * 64 + tid;
    float lr = fminf(Lre[base], -1e-4f);
    float li = Lim[base];
    float pr = Pri[2 * base], pi = Pri[2 * base + 1];
    float br = Bri[2 * base], bi = Bri[2 * base + 1];
    float cr = Cri[2 * base], ci = Cri[2 * base + 1];
    pA[tid] = make_float4(cr * br + ci * bi, cr * bi - ci * br,
                          cr * pr + ci * pi, cr * pi - ci * pr);
    pB[tid] = make_float4(pr * br + pi * bi, pr * bi - pi * br,
                          pr * pr + pi * pi, 0.f);
    pL[tid] = make_float2(lr, li);
  }
  __syncthreads();
  const float istep = expf(-lstep[h]);
  const int m = sub * 256 + tid;
  float sn, cn;
  __sincosf(-(2.0f * PI_F / 4096.0f) * (float)m, &sn, &cn);
  const v2 T = (v2){0.5f * (1.0f + cn), 0.5f * sn};   // (trm, tim)
  const v2 Q = (v2){(1.0f - cn) * istep, -sn * istep};  // (qrm, qim)
  v2 S01 = (v2){0.f, 0.f}, S23 = (v2){0.f, 0.f}, S45 = (v2){0.f, 0.f},
     S67 = (v2){0.f, 0.f};
#pragma unroll 8
  for (int n = 0; n < 64; ++n) {
    float4 a = pA[n];
    float4 b = pB[n];
    v2 L = tov2(pL[n]);
    v2 d = Q - cmul(T, L);
    float inv = __builtin_amdgcn_rcpf(d.x * d.x + d.y * d.y);
    v2 s = d * (v2){inv, -inv};  // (sr, si)
    S01 += cmul((v2){a.x, a.y}, s);
    S23 += cmul((v2){a.z, a.w}, s);
    S45 += cmul((v2){b.x, b.y}, s);
    S67 += (v2){b.z, b.z} * s;
  }
  // epilogue (scalar, once)
  float trm = T.x, tim = T.y;
  float tS11r = trm * S67.x - tim * S67.y;
  float tS11i = trm * S67.y + tim * S67.x;
  float denr = 1.0f + tS11r, deni = tS11i;
  float dinv = 1.0f / (denr * denr + deni * deni);
  float P1r = S23.x * S45.x - S23.y * S45.y;
  float P1i = S23.x * S45.y + S23.y * S45.x;
  float P2r = trm * P1r - tim * P1i;
  float P2i = trm * P1i + tim * P1r;
  float Qr = (P2r * denr + P2i * deni) * dinv;
  float Qi = (P2i * denr - P2r * deni) * dinv;
  atR[h * 4096 + m] = make_float2(S01.x - Qr, S01.y - Qi);
}

// ------- Kernel 1b: atRoots -> alpha/beta table (radix-16 scramble) -----
__global__ __launch_bounds__(256, 4) void k_khat(
    const float2* __restrict__ atR, const float* __restrict__ Dp,
    float4* __restrict__ abt) {
  __shared__ float2 lds[4368];
  const int h = blockIdx.x;
  const int tid = threadIdx.x;
  v2 v[16];
#pragma unroll
  for (int c = 0; c < 16; ++c) v[c] = tov2(atR[h * 4096 + tid + 256 * c]);
  fft4096_regs<1>(v, lds, tid);  // unnormalized inverse -> zK (scrambled)
  const int kb = (tid >> 4) + 16 * (tid & 15);
  float* ldsf = (float*)lds;
  const float s = 1.0f / 4096.0f;
  __syncthreads();
#pragma unroll
  for (int al = 0; al < 16; ++al) ldsf[ad(kb + 256 * al)] = v[al].x * s;
  __syncthreads();
#pragma unroll
  for (int c = 0; c < 8; ++c) {
    int n = tid + 256 * c;
    v[c] = (v2){ldsf[ad(2 * n)], ldsf[ad(2 * n + 1)]};
  }
#pragma unroll
  for (int c = 8; c < 16; ++c) v[c] = (v2){0.f, 0.f};
  fft4096_regs<-1>(v, lds, tid);  // forward; scrambled
  __syncthreads();
#pragma unroll
  for (int al = 0; al < 16; ++al) lds[ad(kb + 256 * al)] = tof2(v[al]);
  __syncthreads();
  const float Dh = Dp[h];
#pragma unroll
  for (int c = 0; c < 16; ++c) {
    int k = kb + 256 * c;
    float2 Zk = lds[ad(k)];
    float2 Zm = lds[ad((4096 - k) & 4095)];
    float Er = 0.5f * (Zk.x + Zm.x), Ei = 0.5f * (Zk.y - Zm.y);
    float Or = 0.5f * (Zk.y + Zm.y), Oi = 0.5f * (Zm.x - Zk.x);
    float s_, c_;
    __sincosf(-(PI_F / 4096.0f) * (float)k, &s_, &c_);
    float Gr = c_ * Or - s_ * Oi, Gi = c_ * Oi + s_ * Or;  // G = W*O
    float ar = (Er + Dh + s_ * Gr) * s;
    float ai = (Ei + s_ * Gi) * s;
    float br = (-c_ * Gi) * s;
    float bi = (c_ * Gr) * s;
    abt[h * 4096 + tid + 256 * c] = make_float4(ar, ai, br, bi);  // scrambled
  }
}

// ---------------- Kernel 2: dual-row FFT convolution ----------------
// 1024 blocks: block i does rows i and i+1024 (same h, batches b and b+8).
__global__ __launch_bounds__(256, 1) void k_conv2(
    const float* __restrict__ u, const float4* __restrict__ abt,
    float* __restrict__ y) {
  __shared__ float4 AB[4096];  // 64 KB: interleaved {rowA,rowB} per bin
  const int i = blockIdx.x;  // 0..1023
  const int h = i & 127;
  const int tid = threadIdx.x;
  const float2* uA = (const float2*)(u + (size_t)i * 4096);
  const float2* uB = (const float2*)(u + (size_t)(i + 1024) * 4096);
  v2 va[16], vb[16];
#pragma unroll
  for (int c = 0; c < 8; ++c) {
    va[c] = tov2(uA[tid + 256 * c]);
    vb[c] = tov2(uB[tid + 256 * c]);
  }
#pragma unroll
  for (int c = 8; c < 16; ++c) {
    va[c] = (v2){0.f, 0.f};
    vb[c] = (v2){0.f, 0.f};
  }
  fft4096_x2<-1>(va, vb, AB, tid);  // forward; v[al]=Z[kb+256al]
  const int kb = (tid >> 4) + 16 * (tid & 15);
  __syncthreads();  // lagging T2 reads done before overwrite
#pragma unroll
  for (int al = 0; al < 16; ++al)
    AB[sw16(kb + 256 * al)] = pk(va[al], vb[al]);
  __syncthreads();
  const float4* __restrict__ abrow = abt + h * 4096;
#pragma unroll
  for (int al = 0; al < 16; ++al) {
    int k = kb + 256 * al;
    float4 zm = AB[sw16((4096 - k) & 4095)];  // {Zma, Zmb} one b128
    float4 ab = abrow[tid + 256 * al];        // one load serves both rows
    v2 alpha = (v2){ab.x, ab.y};
    v2 beta = (v2){ab.z, ab.w};
    // y = alpha*Z + beta*conj(Zm)   (packed: 2 cmul + add per row)
    va[al] = cmul(alpha, va[al]) + cmulcj(beta, (v2){zm.x, zm.y});
    vb[al] = cmul(alpha, vb[al]) + cmulcj(beta, (v2){zm.z, zm.w});
  }
  fft4096_x2_s2n<1>(va, vb, AB, tid);  // inverse (scale folded in ab)
  float2* yA = (float2*)(y + (size_t)i * 4096);
  float2* yB = (float2*)(y + (size_t)(i + 1024) * 4096);
#pragma unroll
  for (int c = 0; c < 8; ++c) {
    yA[tid + 256 * c] = tof2(va[c]);
    yB[tid + 256 * c] = tof2(vb[c]);
  }
}

extern "C" void kernel_launch(void* const* d_in, const int* in_sizes, int n_in,
                              void* d_out, int out_size, void* d_ws,
                              size_t ws_size, hipStream_t stream) {
  (void)in_sizes; (void)n_in; (void)out_size; (void)ws_size;
  const float* u = (const float*)d_in[0];
  const float* Lre = (const float*)d_in[1];
  const float* Lim = (const float*)d_in[2];
  const float* Pri = (const float*)d_in[3];
  const float* Bri = (const float*)d_in[4];
  const float* Cri = (const float*)d_in[5];
  const float* lst = (const float*)d_in[6];
  const float* Dp = (const float*)d_in[7];
  float* y = (float*)d_out;
  float2* atR = (float2*)d_ws;                                     // 4 MiB
  float4* abt = (float4*)((char*)d_ws + (size_t)4 * 1024 * 1024);  // 8 MiB

  k_cauchy<<<2048, 256, 0, stream>>>(Lre, Lim, Pri, Bri, Cri, lst, atR);
  k_khat<<<128, 256, 0, stream>>>(atR, Dp, abt);
  k_conv2<<<1024, 256, 0, stream>>>(u, abt, y);
}